// Round 6
// baseline (167.732 us; speedup 1.0000x reference)
//
#include <hip/hip_runtime.h>

#define Bn 16
#define Cn 64
#define Hn 128
#define Wn 128
#define HWn (Hn * Wn)

typedef __attribute__((ext_vector_type(8))) short  short8;   // 8 bf16 (A/B frag)
typedef __attribute__((ext_vector_type(4))) float  floatx4;  // C/D frag
using int32x4 = int __attribute__((ext_vector_type(4)));

__device__ float
llvm_amdgcn_raw_buffer_load_fp32(int32x4 srsrc, int voffset, int soffset,
                                 int glc_slc) __asm("llvm.amdgcn.raw.buffer.load.f32");

__device__ __forceinline__ int32x4 make_rsrc(const void* p, int bytes) {
    int32x4 r;
    r.x = (int)(unsigned)(uintptr_t)p;
    r.y = (int)((uintptr_t)p >> 32);   // stride=0
    r.z = bytes;                        // num_records
    r.w = 0x00020000;                   // raw dword SRD
    return r;
}

__device__ __forceinline__ unsigned short f2bf(float f) {  // RNE f32->bf16
    unsigned u = __float_as_uint(f);
    u += 0x7fffu + ((u >> 16) & 1u);
    return (unsigned short)(u >> 16);
}
__device__ __forceinline__ float lrelu(float v) { return v >= 0.f ? v : 0.1f * v; }

// ---------------------------------------------------------------------------
// Kernel-gen (R5 structure, proven ~fast): direct per-thread dot-64s.
// Output layout changed for the MFMA consumer:
//   kernT[b][tap][c]  (fp32, taps outer so 8 consecutive c per LDS read)
//   WcBF [o][c]       (bf16 RNE, row-major = MFMA A-operand friendly)
// ---------------------------------------------------------------------------
__global__ __launch_bounds__(192)
void gen_kern5(const float* __restrict__ d,
               const float* __restrict__ Wk1,
               const float* __restrict__ Wk2,
               const float* __restrict__ Wc,
               float* __restrict__ kernT,            // ws: [16][9][64]
               unsigned short* __restrict__ WcBF) {  // ws: [64][64] bf16
    const int b = blockIdx.x;   // 16
    const int r = blockIdx.y;   // 3
    const int t = threadIdx.x;  // 192
    __shared__ float hid_s[64];

    if (t < 64) {
        const float4* __restrict__ w4 = (const float4*)(Wk1 + (size_t)t * 64);
        const float*  __restrict__ db = d + b * 64;
        float s0 = 0.f, s1 = 0.f, s2 = 0.f, s3 = 0.f;
        #pragma unroll
        for (int j = 0; j < 16; ++j) {
            const float4 wv = w4[j];
            s0 += db[4 * j + 0] * wv.x;
            s1 += db[4 * j + 1] * wv.y;
            s2 += db[4 * j + 2] * wv.z;
            s3 += db[4 * j + 3] * wv.w;
        }
        const float s = (s0 + s1) + (s2 + s3);
        hid_s[t] = lrelu(s);
    }
    __syncthreads();

    {
        const int o = r * 192 + t;                   // 576 = 3*192
        const float4* __restrict__ w4 = (const float4*)(Wk2 + (size_t)o * 64);
        const float4* __restrict__ h4 = (const float4*)hid_s;
        float s0 = 0.f, s1 = 0.f, s2 = 0.f, s3 = 0.f;
        #pragma unroll
        for (int j = 0; j < 16; ++j) {
            const float4 wv = w4[j];
            const float4 hv = h4[j];
            s0 += hv.x * wv.x;
            s1 += hv.y * wv.y;
            s2 += hv.z * wv.z;
            s3 += hv.w * wv.w;
        }
        const int c = o / 9, tap = o - c * 9;
        kernT[b * 576 + tap * 64 + c] = (s0 + s1) + (s2 + s3);
    }

    if (b == 0 && r == 0) {
        for (int idx = t; idx < 4096; idx += 192)
            WcBF[idx] = f2bf(Wc[idx]);
    }
}

// ---------------------------------------------------------------------------
// Main fused conv, MFMA 1x1. Per block: batch b, one image row h (128 px).
// 4 waves x 2 tiles of 16 px. Per 16-px tile, per kk (c-half of 32):
//   each lane computes dw(c = kk*32 + q*8 + j, pixel = w0 + (lane&15)) in
//   fp32 (9 buffer-OOB taps, kern weights from LDS), lrelu, RNE-pack into
//   the B-frag (n=lane&15, k=q*8+j); Wc bf16 A-frags (m=o) are persistent;
//   4 MFMA (o-tiles) accumulate D. D layout: col=pixel, row=o=q*4+reg.
// VALU/iter collapses from 64 acc-FMAs to 4 MFMA issues.
// ---------------------------------------------------------------------------
__global__ __launch_bounds__(256, 3)
void da_mfma(const float* __restrict__ x,
             const float* __restrict__ kernT,
             const unsigned short* __restrict__ WcBF,
             const float* __restrict__ bc,
             float* __restrict__ out) {
    const int t    = threadIdx.x;
    const int lane = t & 63;
    const int wv   = t >> 6;           // wave 0..3
    const int col  = lane & 15;        // pixel within tile (n)
    const int q    = lane >> 4;        // quad 0..3
    const int bx   = blockIdx.x;       // 128
    const int h    = ((bx & 7) << 4) | (bx >> 3);   // XCD swizzle: bands of 16 rows
    const int b    = blockIdx.y;       // 16

    __shared__ float kl[9 * 64];       // kernT[b] staged

    for (int i = t; i < 576; i += 256) kl[i] = kernT[b * 576 + i];

    // A-frags (Wc bf16): lane holds Wc[o = m*16+col][kk*32 + q*8 + j]
    short8 afr[4][2];
    #pragma unroll
    for (int m = 0; m < 4; ++m)
        #pragma unroll
        for (int kk = 0; kk < 2; ++kk)
            afr[m][kk] = *(const short8*)(WcBF + (m * 16 + col) * 64 + kk * 32 + q * 8);

    // bias for this lane's D rows: o = m*16 + q*4 + r
    floatx4 bias[4];
    #pragma unroll
    for (int m = 0; m < 4; ++m)
        bias[m] = *(const floatx4*)(bc + m * 16 + q * 4);

    __syncthreads();

    const float* __restrict__ xb = x + (size_t)b * Cn * HWn;
    const int32x4 rs = make_rsrc(xb, Cn * HWn * 4);

    // vertical tap offsets (bytes), border -> OOB sentinel
    int rofsB[3];
    #pragma unroll
    for (int i = 0; i < 3; ++i) {
        const int hh = h + i - 1;
        rofsB[i] = (hh >= 0 && hh < Hn) ? hh * (Wn * 4) : 0x10000000;
    }

    const int ckbase = q * 8;          // channel sub-base within a kk-half

    #pragma unroll
    for (int tt = 0; tt < 2; ++tt) {
        const int w0 = (wv << 5) + (tt << 4);
        const int w  = w0 + col;

        int cofsB[3];
        #pragma unroll
        for (int i = 0; i < 3; ++i) {
            const int ww = w - 1 + i;
            cofsB[i] = (ww >= 0 && ww < Wn) ? ww * 4 : 0x10000000;
        }
        int voff[9];
        #pragma unroll
        for (int rr = 0; rr < 3; ++rr)
            #pragma unroll
            for (int cc = 0; cc < 3; ++cc)
                voff[rr * 3 + cc] = rofsB[rr] + cofsB[cc];

        floatx4 acc[4];
        #pragma unroll
        for (int m = 0; m < 4; ++m) acc[m] = bias[m];

        #pragma unroll
        for (int kk = 0; kk < 2; ++kk) {
            const int cb = (kk * 32 + ckbase) << 16;   // *HWn*4 = 64KB/channel
            float dv0 = 0.f, dv1 = 0.f, dv2 = 0.f, dv3 = 0.f;
            float dv4 = 0.f, dv5 = 0.f, dv6 = 0.f, dv7 = 0.f;
            #pragma unroll
            for (int i = 0; i < 9; ++i) {
                const floatx4* kr =
                    (const floatx4*)(kl + i * 64 + kk * 32 + ckbase);
                const floatx4 k0 = kr[0];
                const floatx4 k1 = kr[1];
                const int vo = voff[i];
                const float x0 = llvm_amdgcn_raw_buffer_load_fp32(rs, cb + 0x00000 + vo, 0, 0);
                const float x1 = llvm_amdgcn_raw_buffer_load_fp32(rs, cb + 0x10000 + vo, 0, 0);
                const float x2 = llvm_amdgcn_raw_buffer_load_fp32(rs, cb + 0x20000 + vo, 0, 0);
                const float x3 = llvm_amdgcn_raw_buffer_load_fp32(rs, cb + 0x30000 + vo, 0, 0);
                const float x4 = llvm_amdgcn_raw_buffer_load_fp32(rs, cb + 0x40000 + vo, 0, 0);
                const float x5 = llvm_amdgcn_raw_buffer_load_fp32(rs, cb + 0x50000 + vo, 0, 0);
                const float x6 = llvm_amdgcn_raw_buffer_load_fp32(rs, cb + 0x60000 + vo, 0, 0);
                const float x7 = llvm_amdgcn_raw_buffer_load_fp32(rs, cb + 0x70000 + vo, 0, 0);
                dv0 += x0 * k0.x;  dv1 += x1 * k0.y;
                dv2 += x2 * k0.z;  dv3 += x3 * k0.w;
                dv4 += x4 * k1.x;  dv5 += x5 * k1.y;
                dv6 += x6 * k1.z;  dv7 += x7 * k1.w;
            }
            short8 bfr;
            bfr[0] = (short)f2bf(lrelu(dv0));
            bfr[1] = (short)f2bf(lrelu(dv1));
            bfr[2] = (short)f2bf(lrelu(dv2));
            bfr[3] = (short)f2bf(lrelu(dv3));
            bfr[4] = (short)f2bf(lrelu(dv4));
            bfr[5] = (short)f2bf(lrelu(dv5));
            bfr[6] = (short)f2bf(lrelu(dv6));
            bfr[7] = (short)f2bf(lrelu(dv7));
            #pragma unroll
            for (int m = 0; m < 4; ++m)
                acc[m] = __builtin_amdgcn_mfma_f32_16x16x32_bf16(
                             afr[m][kk], bfr, acc[m], 0, 0, 0);
        }

        // store: lane writes o = m*16 + q*4 + r at pixel (h, w)
        float* __restrict__ ob = out + (size_t)b * Cn * HWn + h * Wn + w;
        #pragma unroll
        for (int m = 0; m < 4; ++m) {
            const int ob0 = m * 16 + q * 4;
            ob[(size_t)(ob0 + 0) * HWn] = acc[m][0];
            ob[(size_t)(ob0 + 1) * HWn] = acc[m][1];
            ob[(size_t)(ob0 + 2) * HWn] = acc[m][2];
            ob[(size_t)(ob0 + 3) * HWn] = acc[m][3];
        }
    }
}

// ---------------------------------------------------------------------------
extern "C" void kernel_launch(void* const* d_in, const int* in_sizes, int n_in,
                              void* d_out, int out_size, void* d_ws, size_t ws_size,
                              hipStream_t stream) {
    const float* x   = (const float*)d_in[0];
    const float* d   = (const float*)d_in[1];
    const float* Wk1 = (const float*)d_in[2];
    const float* Wk2 = (const float*)d_in[3];
    const float* Wc  = (const float*)d_in[4];
    const float* bc  = (const float*)d_in[5];
    float* out = (float*)d_out;
    float*          kernT = (float*)d_ws;                      // 16*576 fp32
    unsigned short* WcBF  = (unsigned short*)((float*)d_ws + Bn * 576); // 64*64 bf16

    gen_kern5<<<dim3(Bn, 3), dim3(192), 0, stream>>>(d, Wk1, Wk2, Wc, kernT, WcBF);
    da_mfma<<<dim3(Hn, Bn), dim3(256), 0, stream>>>(x, kernT, WcBF, bc, out);
}

// Round 7
// 138.200 us; speedup vs baseline: 1.2137x; 1.2137x over previous
//
#include <hip/hip_runtime.h>

#define Bn 16
#define Cn 64
#define Hn 128
#define Wn 128
#define HWn (Hn * Wn)

typedef __attribute__((ext_vector_type(8)))  short  short8;    // 8 bf16
typedef __attribute__((ext_vector_type(16))) float  floatx16;  // 32x32 C/D
typedef __attribute__((ext_vector_type(4)))  float  floatx4;
using int32x4 = int __attribute__((ext_vector_type(4)));

__device__ float
llvm_amdgcn_raw_buffer_load_fp32(int32x4 srsrc, int voffset, int soffset,
                                 int aux) __asm("llvm.amdgcn.raw.buffer.load.f32");
__device__ floatx4
llvm_amdgcn_raw_buffer_load_v4f32(int32x4 srsrc, int voffset, int soffset,
                                  int aux) __asm("llvm.amdgcn.raw.buffer.load.v4f32");

__device__ __forceinline__ int32x4 make_rsrc(const void* p, int bytes) {
    int32x4 r;
    r.x = (int)(unsigned)(uintptr_t)p;
    r.y = (int)((uintptr_t)p >> 32);   // stride=0
    r.z = bytes;                        // num_records
    r.w = 0x00020000;                   // raw dword SRD
    return r;
}

__device__ __forceinline__ unsigned short f2bf(float f) {  // RNE f32->bf16
    unsigned u = __float_as_uint(f);
    u += 0x7fffu + ((u >> 16) & 1u);
    return (unsigned short)(u >> 16);
}
__device__ __forceinline__ float lrelu(float v) { return v >= 0.f ? v : 0.1f * v; }

// ---------------------------------------------------------------------------
// Kernel-gen (R5 proven structure). Outputs:
//   kernP[b][c][12]  fp32, taps 0..8 at [0..8], pad [9..11] (16B-aligned rows)
//   WcBF [o][c]      bf16 RNE (row-major, A-operand friendly)
// ---------------------------------------------------------------------------
__global__ __launch_bounds__(192)
void gen_kern6(const float* __restrict__ d,
               const float* __restrict__ Wk1,
               const float* __restrict__ Wk2,
               const float* __restrict__ Wc,
               float* __restrict__ kernP,            // ws: [16][64][12]
               unsigned short* __restrict__ WcBF) {  // ws: [64][64] bf16
    const int b = blockIdx.x;   // 16
    const int r = blockIdx.y;   // 3
    const int t = threadIdx.x;  // 192
    __shared__ float hid_s[64];

    if (t < 64) {
        const float4* __restrict__ w4 = (const float4*)(Wk1 + (size_t)t * 64);
        const float*  __restrict__ db = d + b * 64;
        float s0 = 0.f, s1 = 0.f, s2 = 0.f, s3 = 0.f;
        #pragma unroll
        for (int j = 0; j < 16; ++j) {
            const float4 wv = w4[j];
            s0 += db[4 * j + 0] * wv.x;
            s1 += db[4 * j + 1] * wv.y;
            s2 += db[4 * j + 2] * wv.z;
            s3 += db[4 * j + 3] * wv.w;
        }
        hid_s[t] = lrelu((s0 + s1) + (s2 + s3));
    }
    __syncthreads();

    {
        const int o = r * 192 + t;                   // 576 = 3*192
        const float4* __restrict__ w4 = (const float4*)(Wk2 + (size_t)o * 64);
        const float4* __restrict__ h4 = (const float4*)hid_s;
        float s0 = 0.f, s1 = 0.f, s2 = 0.f, s3 = 0.f;
        #pragma unroll
        for (int j = 0; j < 16; ++j) {
            const float4 wv = w4[j];
            const float4 hv = h4[j];
            s0 += hv.x * wv.x;
            s1 += hv.y * wv.y;
            s2 += hv.z * wv.z;
            s3 += hv.w * wv.w;
        }
        const int c = o / 9, tap = o - c * 9;
        kernP[b * 768 + c * 12 + tap] = (s0 + s1) + (s2 + s3);
    }

    if (b == 0 && r == 0) {
        for (int idx = t; idx < 4096; idx += 192)
            WcBF[idx] = f2bf(Wc[idx]);
    }
}

// ---------------------------------------------------------------------------
// Main fused conv: per block (h,b), 128 px row, all 64 o.
// Per channel-group g (16 ch = one K=16 MFMA step):
//   STAGE: thread (ch=t>>4, oct=t&15) loads x rows h-1..h+1 x 8 px ONCE
//     (buffer-OOB dwordx4; border rows auto-zero), computes column sums
//     t_dx[p] = sum_dy k[dy][dx]*x[row][p] (9 FMA/px), writes t to LDS
//     (b128, rows padded with zero slots at p=-1 / p=128).
//   COMPUTE: lane (px=wv*32+(lane&31), kh=lane>>5) reads 3 t values per ch
//     (dw = t0[p-1]+t1[p]+t2[p+1]), lrelu, RNE-pack -> B-frag;
//     2x mfma_32x32x16_bf16 with persistent-ish Wc A-frags.
// D layout (m101-verified): col=lane&31=px, row=(reg&3)+8*(reg>>2)+4*kh
//   -> 32-px full-128B-line stores (fixes R6's 92.8MB WRITE_SIZE).
// LDS 26.1 KB single-buffered; 2 barriers/group.
// ---------------------------------------------------------------------------
__global__ __launch_bounds__(256)
void da_mfma2(const float* __restrict__ x,
              const float* __restrict__ kernP,
              const unsigned short* __restrict__ WcBF,
              const float* __restrict__ bc,
              float* __restrict__ out) {
    const int t    = threadIdx.x;
    const int lane = t & 63;
    const int wv   = t >> 6;            // wave 0..3 -> px tile
    const int col  = lane & 31;         // px within tile / A-B n,m index
    const int kh   = lane >> 5;         // k-half (8 ch)
    const int bx   = blockIdx.x;        // 128
    const int h    = ((bx & 7) << 4) | (bx >> 3);   // XCD-band swizzle
    const int b    = blockIdx.y;        // 16

    __shared__ float tl[16 * 3 * 136];  // [ch][dx][136]: px p at 4+p, zeros at 3/132

    // vertical row byte-offsets; border -> OOB sentinel (loads return 0)
    int rofsB[3];
    #pragma unroll
    for (int i = 0; i < 3; ++i) {
        const int hh = h + i - 1;
        rofsB[i] = (hh >= 0 && hh < Hn) ? hh * (Wn * 4) : 0x10000000;
    }

    const int32x4 rs = make_rsrc(x + (size_t)b * Cn * HWn, Cn * HWn * 4);

    // acc init = bias (D row o = m*32 + (r&3)+8*(r>>2)+4*kh)
    floatx16 acc[2];
    #pragma unroll
    for (int m = 0; m < 2; ++m)
        #pragma unroll
        for (int r = 0; r < 16; ++r)
            acc[m][r] = bc[m * 32 + (r & 3) + 8 * (r >> 2) + 4 * kh];

    // staging mapping
    const int sch = t >> 4;             // 0..15 (channel within group)
    const int px0 = (t & 15) * 8;       // 8-px octet
    const float* __restrict__ kp = kernP + b * 768;

    const int px = wv * 32 + col;

    for (int g = 0; g < 4; ++g) {
        // ---- STAGE ----
        const int c = g * 16 + sch;
        const floatx4* k4 = (const floatx4*)(kp + c * 12);
        const floatx4 k0 = k4[0];                 // taps 0..3
        const floatx4 k1 = k4[1];                 // taps 4..7
        const float   k8 = ((const float*)k4)[8]; // tap 8

        float xa[3][8];
        #pragma unroll
        for (int r = 0; r < 3; ++r) {
            const int vo = (c << 16) + rofsB[r] + px0 * 4;
            const floatx4 va = llvm_amdgcn_raw_buffer_load_v4f32(rs, vo, 0, 0);
            const floatx4 vb = llvm_amdgcn_raw_buffer_load_v4f32(rs, vo + 16, 0, 0);
            xa[r][0] = va.x; xa[r][1] = va.y; xa[r][2] = va.z; xa[r][3] = va.w;
            xa[r][4] = vb.x; xa[r][5] = vb.y; xa[r][6] = vb.z; xa[r][7] = vb.w;
        }

        float t0[8], t1[8], t2[8];
        #pragma unroll
        for (int i = 0; i < 8; ++i) {
            t0[i] = k0.x * xa[0][i] + k0.w * xa[1][i] + k1.z * xa[2][i]; // taps 0,3,6
            t1[i] = k0.y * xa[0][i] + k1.x * xa[1][i] + k1.w * xa[2][i]; // taps 1,4,7
            t2[i] = k0.z * xa[0][i] + k1.y * xa[1][i] + k8   * xa[2][i]; // taps 2,5,8
        }
        {
            const int base = (sch * 3) * 136 + 4 + px0;
            *(float4*)&tl[base]             = make_float4(t0[0], t0[1], t0[2], t0[3]);
            *(float4*)&tl[base + 4]         = make_float4(t0[4], t0[5], t0[6], t0[7]);
            *(float4*)&tl[base + 136]       = make_float4(t1[0], t1[1], t1[2], t1[3]);
            *(float4*)&tl[base + 140]       = make_float4(t1[4], t1[5], t1[6], t1[7]);
            *(float4*)&tl[base + 272]       = make_float4(t2[0], t2[1], t2[2], t2[3]);
            *(float4*)&tl[base + 276]       = make_float4(t2[4], t2[5], t2[6], t2[7]);
        }
        if (t < 96) {   // zero slots: p=-1 (idx 3) and p=128 (idx 132)
            const int ch = t / 6, rem = t - ch * 6;
            const int dx = rem >> 1, side = rem & 1;
            tl[(ch * 3 + dx) * 136 + (side ? 132 : 3)] = 0.f;
        }
        __syncthreads();

        // ---- COMPUTE ----
        short8 bfr;
        #pragma unroll
        for (int j = 0; j < 8; ++j) {
            const int cl = kh * 8 + j;
            const int base = (cl * 3) * 136 + 4 + px;
            const float dw = tl[base - 1]            // t0[p-1]
                           + tl[base + 136]          // t1[p]
                           + tl[base + 273];         // t2[p+1]
            bfr[j] = (short)f2bf(lrelu(dw));
        }
        const short8 a0 = *(const short8*)(WcBF + (0 * 32 + col) * 64 + g * 16 + kh * 8);
        const short8 a1 = *(const short8*)(WcBF + (1 * 32 + col) * 64 + g * 16 + kh * 8);
        acc[0] = __builtin_amdgcn_mfma_f32_32x32x16_bf16(a0, bfr, acc[0], 0, 0, 0);
        acc[1] = __builtin_amdgcn_mfma_f32_32x32x16_bf16(a1, bfr, acc[1], 0, 0, 0);
        __syncthreads();    // protect tl before next group's overwrite
    }

    // ---- STORE: full 128B lines (32 px contiguous per o-row) ----
    float* __restrict__ ob = out + (size_t)b * Cn * HWn + h * Wn + px;
    #pragma unroll
    for (int m = 0; m < 2; ++m)
        #pragma unroll
        for (int r = 0; r < 16; ++r) {
            const int o = m * 32 + (r & 3) + 8 * (r >> 2) + 4 * kh;
            ob[(size_t)o * HWn] = acc[m][r];
        }
}

// ---------------------------------------------------------------------------
extern "C" void kernel_launch(void* const* d_in, const int* in_sizes, int n_in,
                              void* d_out, int out_size, void* d_ws, size_t ws_size,
                              hipStream_t stream) {
    const float* x   = (const float*)d_in[0];
    const float* d   = (const float*)d_in[1];
    const float* Wk1 = (const float*)d_in[2];
    const float* Wk2 = (const float*)d_in[3];
    const float* Wc  = (const float*)d_in[4];
    const float* bc  = (const float*)d_in[5];
    float* out = (float*)d_out;
    float*          kernP = (float*)d_ws;                         // 16*768 fp32
    unsigned short* WcBF  = (unsigned short*)((float*)d_ws + Bn * 768); // 64*64 bf16

    gen_kern6<<<dim3(Bn, 3), dim3(192), 0, stream>>>(d, Wk1, Wk2, Wc, kernP, WcBF);
    da_mfma2<<<dim3(Hn, Bn), dim3(256), 0, stream>>>(x, kernP, WcBF, bc, out);
}